// Round 14
// baseline (1054.844 us; speedup 1.0000x reference)
//
#include <hip/hip_runtime.h>

#define N_NODES  100000
#define NNZ_FEAT 2000000
#define N_EDGES  1600000
#define IN_DIM   256
#define OUT_DIM  64

// X tile-sort geometry
#define TILE_ROWS   16
#define NBINS       (N_NODES / TILE_ROWS)   // 6250
#define GX          128                      // count/rank blocks
#define CHUNK       (NNZ_FEAT / GX)          // 15625 exactly
#define CNTS_X      (NBINS * GX)             // 800000

__device__ __forceinline__ bool keep_entry(float u) {
    // exact replication of reference: floor(0.9f + u) >= 1.0f
    return floorf(0.9f + u) >= 1.0f;
}

// ---------------- X tile-sort: count pass (LDS histogram, NO global atomics)
__global__ void __launch_bounds__(256) count_x(
        const int* __restrict__ xr, const float* __restrict__ du,
        int* __restrict__ counts /* [bin*GX + g] */) {
    __shared__ int hist[NBINS];
    int t = threadIdx.x, g = blockIdx.x;
    for (int b = t; b < NBINS; b += 256) hist[b] = 0;
    __syncthreads();
    int s = g * CHUNK, e = s + CHUNK;
    for (int i = s + t; i < e; i += 256) {
        if (keep_entry(du[i])) atomicAdd(&hist[xr[i] >> 4], 1);  // LDS atomic
    }
    __syncthreads();
    for (int b = t; b < NBINS; b += 256) counts[b * GX + g] = hist[b];
}

// ---------------- X tile-sort: rank+scatter pass (LDS return-atomics only)
__global__ void __launch_bounds__(256) rank_scatter_x(
        const int* __restrict__ xr, const int* __restrict__ xc,
        const float* __restrict__ xv, const float* __restrict__ du,
        const int* __restrict__ base /* scanned counts */,
        int2* __restrict__ pkX) {
    __shared__ int cur[NBINS];
    int t = threadIdx.x, g = blockIdx.x;
    for (int b = t; b < NBINS; b += 256) cur[b] = base[b * GX + g];
    __syncthreads();
    const float SCL = (float)(1.0 / 0.9);
    int s = g * CHUNK, e = s + CHUNK;
    for (int i = s + t; i < e; i += 256) {
        if (!keep_entry(du[i])) continue;
        int r = xr[i];
        int pos = atomicAdd(&cur[r >> 4], 1);          // LDS rtn atomic = global pos
        int key = ((r & (TILE_ROWS - 1)) << 8) | xc[i]; // local row | col (<256)
        pkX[pos] = make_int2(__float_as_int(xv[i] * SCL), key);
    }
}

// tile_start[b] = base[b*GX]  (segment starts; [NBINS] slot written by scan lvl2)
__global__ void extract_tile_start(const int* __restrict__ base,
                                   int* __restrict__ tile_start) {
    int b = blockIdx.x * blockDim.x + threadIdx.x;
    if (b < NBINS) tile_start[b] = base[b * GX];
}

// ---------------- SpMM1 on tile-sorted X: LDS f32 accumulation -------------
// One block per 16-row tile; no global atomics, no h memset needed
// (rows partition exactly across blocks; zero-entry rows stay 0).
__global__ void __launch_bounds__(256) spmm1_tile(
        const int2* __restrict__ pk, const int* __restrict__ tile_start,
        const float* __restrict__ W, float* __restrict__ h) {
    __shared__ float ht[TILE_ROWS * OUT_DIM];  // 4KB
    int t = threadIdx.x, wave = t >> 6, lane = t & 63;
    ht[t] = 0.f; ht[t + 256] = 0.f; ht[t + 512] = 0.f; ht[t + 768] = 0.f;
    __syncthreads();
    int s = tile_start[blockIdx.x], e = tile_start[blockIdx.x + 1];
    for (int j = s + wave; j < e; j += 4) {
        int2 p = pk[j];                       // wave-uniform 8B
        float v = __int_as_float(p.x);
        int lr = p.y >> 8;
        int c  = p.y & 255;
        atomicAdd(&ht[lr * OUT_DIM + lane], v * W[c * OUT_DIM + lane]); // ds_add_f32
    }
    __syncthreads();
    int rbase = blockIdx.x * TILE_ROWS;
    for (int q = 0; q < 4; ++q) {
        int rr = wave * 4 + q;
        h[(size_t)(rbase + rr) * OUT_DIM + lane] = ht[rr * OUT_DIM + lane];
    }
}

// ---------------- A-side (proven R8/R9 kernels) ----------------

__global__ void hist_a(const int* __restrict__ ar,
                       int* __restrict__ cnt_a, int* __restrict__ offs_a) {
    int e = blockIdx.x * blockDim.x + threadIdx.x;
    if (e < N_EDGES) offs_a[e] = atomicAdd(&cnt_a[ar[e]], 1);
}

// generic 2-level scan building blocks (1024 elems/block)
__global__ void scan_pass1(const int* __restrict__ cnt, int* __restrict__ excl,
                           int* __restrict__ bsum, int n) {
    __shared__ int sh[256];
    int t = threadIdx.x;
    int base = blockIdx.x * 1024 + t * 4;
    int v0 = (base + 0 < n) ? cnt[base + 0] : 0;
    int v1 = (base + 1 < n) ? cnt[base + 1] : 0;
    int v2 = (base + 2 < n) ? cnt[base + 2] : 0;
    int v3 = (base + 3 < n) ? cnt[base + 3] : 0;
    int tsum = v0 + v1 + v2 + v3;
    sh[t] = tsum;
    __syncthreads();
    for (int off = 1; off < 256; off <<= 1) {
        int x = (t >= off) ? sh[t - off] : 0;
        __syncthreads();
        sh[t] += x;
        __syncthreads();
    }
    int texcl = sh[t] - tsum;
    if (base + 0 < n) excl[base + 0] = texcl;
    if (base + 1 < n) excl[base + 1] = texcl + v0;
    if (base + 2 < n) excl[base + 2] = texcl + v0 + v1;
    if (base + 3 < n) excl[base + 3] = texcl + v0 + v1 + v2;
    if (t == 255) bsum[blockIdx.x] = sh[255];
}

__global__ void scan_pass3(int* __restrict__ arr, const int* __restrict__ bS, int n) {
    int i = blockIdx.x * blockDim.x + threadIdx.x;
    if (i < n) arr[i] += bS[i >> 10];
}

__global__ void scatter_a(const int* __restrict__ ar, const int* __restrict__ ac,
                          const float* __restrict__ av,
                          const int* __restrict__ startA, const int* __restrict__ offs_a,
                          int2* __restrict__ pkA) {
    int e = blockIdx.x * blockDim.x + threadIdx.x;
    if (e < N_EDGES) {
        int pos = startA[ar[e]] + offs_a[e];
        pkA[pos] = make_int2(__float_as_int(av[e]), ac[e]);
    }
}

// one wave per row; out[r,l] = relu( sum_j a_j * h[c_j, l] )  (8/4/2/1 ladder)
__global__ void __launch_bounds__(256) spmm2_csr(
        const int* __restrict__ startArr, const int2* __restrict__ pk,
        const float* __restrict__ h, float* __restrict__ out) {
    int wid  = (blockIdx.x * blockDim.x + threadIdx.x) >> 6;
    int lane = threadIdx.x & 63;
    if (wid >= N_NODES) return;
    int s = startArr[wid], e = startArr[wid + 1];
    float acc = 0.0f;
    int j = s;
    for (; j + 8 <= e; j += 8) {
        int2 p0 = pk[j + 0]; int2 p1 = pk[j + 1];
        int2 p2 = pk[j + 2]; int2 p3 = pk[j + 3];
        int2 p4 = pk[j + 4]; int2 p5 = pk[j + 5];
        int2 p6 = pk[j + 6]; int2 p7 = pk[j + 7];
        float g0 = h[p0.y * OUT_DIM + lane];
        float g1 = h[p1.y * OUT_DIM + lane];
        float g2 = h[p2.y * OUT_DIM + lane];
        float g3 = h[p3.y * OUT_DIM + lane];
        float g4 = h[p4.y * OUT_DIM + lane];
        float g5 = h[p5.y * OUT_DIM + lane];
        float g6 = h[p6.y * OUT_DIM + lane];
        float g7 = h[p7.y * OUT_DIM + lane];
        acc = fmaf(__int_as_float(p0.x), g0, acc);
        acc = fmaf(__int_as_float(p1.x), g1, acc);
        acc = fmaf(__int_as_float(p2.x), g2, acc);
        acc = fmaf(__int_as_float(p3.x), g3, acc);
        acc = fmaf(__int_as_float(p4.x), g4, acc);
        acc = fmaf(__int_as_float(p5.x), g5, acc);
        acc = fmaf(__int_as_float(p6.x), g6, acc);
        acc = fmaf(__int_as_float(p7.x), g7, acc);
    }
    if (j + 4 <= e) {
        int2 p0 = pk[j + 0]; int2 p1 = pk[j + 1];
        int2 p2 = pk[j + 2]; int2 p3 = pk[j + 3];
        float g0 = h[p0.y * OUT_DIM + lane];
        float g1 = h[p1.y * OUT_DIM + lane];
        float g2 = h[p2.y * OUT_DIM + lane];
        float g3 = h[p3.y * OUT_DIM + lane];
        acc = fmaf(__int_as_float(p0.x), g0, acc);
        acc = fmaf(__int_as_float(p1.x), g1, acc);
        acc = fmaf(__int_as_float(p2.x), g2, acc);
        acc = fmaf(__int_as_float(p3.x), g3, acc);
        j += 4;
    }
    if (j + 2 <= e) {
        int2 p0 = pk[j + 0]; int2 p1 = pk[j + 1];
        float g0 = h[p0.y * OUT_DIM + lane];
        float g1 = h[p1.y * OUT_DIM + lane];
        acc = fmaf(__int_as_float(p0.x), g0, acc);
        acc = fmaf(__int_as_float(p1.x), g1, acc);
        j += 2;
    }
    if (j < e) {
        int2 p = pk[j];
        acc = fmaf(__int_as_float(p.x), h[p.y * OUT_DIM + lane], acc);
    }
    out[wid * OUT_DIM + lane] = fmaxf(acc, 0.0f);
}

// ---------------- launch ----------------

extern "C" void kernel_launch(void* const* d_in, const int* in_sizes, int n_in,
                              void* d_out, int out_size, void* d_ws, size_t ws_size,
                              hipStream_t stream) {
    const int*   x_rows       = (const int*)d_in[0];
    const int*   x_cols       = (const int*)d_in[1];
    const float* x_values     = (const float*)d_in[2];
    const int*   adj_rows     = (const int*)d_in[3];
    const int*   adj_cols     = (const int*)d_in[4];
    const float* adj_values   = (const float*)d_in[5];
    const float* drop_uniform = (const float*)d_in[6];
    const float* weights      = (const float*)d_in[7];
    float* out = (float*)d_out;

    // ---- workspace carve (256B-aligned), ~72MB ----
    char* base = (char*)d_ws;
    size_t off = 0;
    auto carve = [&](size_t bytes) -> void* {
        void* p = base + off;
        off += (bytes + 255) & ~(size_t)255;
        return p;
    };
    float* h        = (float*)carve((size_t)N_NODES * OUT_DIM * sizeof(float)); // 25.6MB
    int*   counts_x = (int*)carve((size_t)CNTS_X * sizeof(int));   // 3.2MB (fully overwritten)
    int*   base_x   = (int*)carve((size_t)CNTS_X * sizeof(int));   // 3.2MB (scanned)
    int*   tile_st  = (int*)carve((NBINS + 1) * sizeof(int));
    int*   bsum_x   = (int*)carve(1024 * sizeof(int));
    int*   bsumS_x  = (int*)carve(1024 * sizeof(int));
    int*   cnt_a    = (int*)carve(N_NODES * sizeof(int));
    int*   start_a  = (int*)carve((N_NODES + 1) * sizeof(int));
    int*   bsum_a   = (int*)carve(1024 * sizeof(int));
    int*   bsumS_a  = (int*)carve(1024 * sizeof(int));
    int*   offs_a   = (int*)carve((size_t)N_EDGES * sizeof(int));    // 6.4MB
    int2*  pk_x     = (int2*)carve((size_t)NNZ_FEAT * sizeof(int2)); // 16MB
    int2*  pk_a     = (int2*)carve((size_t)N_EDGES * sizeof(int2));  // 12.8MB
    (void)ws_size;

    // only cnt_a needs zeroing (counts_x fully overwritten; h fully covered)
    hipMemsetAsync(cnt_a, 0, N_NODES * sizeof(int), stream);

    // X count (LDS histograms, no global atomics)
    count_x<<<GX, 256, 0, stream>>>(x_rows, drop_uniform, counts_x);

    // A histogram + offset capture (1.6M return-atomics)
    hist_a<<<(N_EDGES + 255) / 256, 256, 0, stream>>>(adj_rows, cnt_a, offs_a);

    // X scan: 800000 elems, bin-major -> base_x; total -> tile_st[NBINS]
    {
        const int NBX = (CNTS_X + 1023) / 1024;  // 782
        scan_pass1<<<NBX, 256, 0, stream>>>(counts_x, base_x, bsum_x, CNTS_X);
        scan_pass1<<<1, 256, 0, stream>>>(bsum_x, bsumS_x, &tile_st[NBINS], NBX);
        scan_pass3<<<(CNTS_X + 255) / 256, 256, 0, stream>>>(base_x, bsumS_x, CNTS_X);
        extract_tile_start<<<(NBINS + 255) / 256, 256, 0, stream>>>(base_x, tile_st);
    }

    // A scan: 100000 elems -> start_a; total -> start_a[N_NODES]
    {
        const int NBA = (N_NODES + 1023) / 1024;  // 98
        scan_pass1<<<NBA, 256, 0, stream>>>(cnt_a, start_a, bsum_a, N_NODES);
        scan_pass1<<<1, 256, 0, stream>>>(bsum_a, bsumS_a, &start_a[N_NODES], NBA);
        scan_pass3<<<(N_NODES + 255) / 256, 256, 0, stream>>>(start_a, bsumS_a, N_NODES);
    }

    // X rank+scatter (LDS cursors; zero global atomics)
    rank_scatter_x<<<GX, 256, 0, stream>>>(
        x_rows, x_cols, x_values, drop_uniform, base_x, pk_x);

    // A scatter (atomic-free)
    scatter_a<<<(N_EDGES + 255) / 256, 256, 0, stream>>>(
        adj_rows, adj_cols, adj_values, start_a, offs_a, pk_a);

    // SpMM1 on tile-sorted X (LDS accumulation; writes all of h)
    spmm1_tile<<<NBINS, 256, 0, stream>>>(pk_x, tile_st, weights, h);

    // SpMM2 gather + fused ReLU
    {
        long long threads = (long long)N_NODES * OUT_DIM;  // 6.4M
        spmm2_csr<<<(unsigned)((threads + 255) / 256), 256, 0, stream>>>(
            start_a, pk_a, h, out);
    }
}